// Round 3
// baseline (248.562 us; speedup 1.0000x reference)
//
#include <hip/hip_runtime.h>
#include <hip/hip_bf16.h>
#include <math.h>

typedef unsigned short u16;

#define BATCH 16384
#define HID   512
#define KDIM  1024   // INPUT + HIDDEN
#define BM    256    // batch rows per block
#define BNG   64     // per-gate cols per block (x4 gates = 256 effective)
#define BK    32     // K per buffer

typedef __bf16 bf16x8 __attribute__((ext_vector_type(8)));
typedef float  floatx4 __attribute__((ext_vector_type(4)));

__device__ __forceinline__ void async_copy16(const void* g, void* l) {
  __builtin_amdgcn_global_load_lds(
      (const __attribute__((address_space(1))) void*)g,
      (__attribute__((address_space(3))) void*)l, 16, 0, 0);
}

__device__ __forceinline__ float fast_sigmoid(float x) {
  return 1.0f / (1.0f + __expf(-x));
}
__device__ __forceinline__ float fast_tanh(float x) {
  float e = __expf(-2.0f * fabsf(x));
  float t = (1.0f - e) / (1.0f + e);
  return x >= 0.0f ? t : -t;
}
__device__ __forceinline__ u16 f2bf(float f) {
  return __builtin_bit_cast(u16, __float2bfloat16(f));
}

// ---------- pre-pass: fp32 -> bf16 packing into workspace (single kernel) ----
__global__ __launch_bounds__(256) void pack_kernel(
    const float* __restrict__ input_, const float* __restrict__ prev_h,
    const float* __restrict__ Wi, const float* __restrict__ Wf,
    const float* __restrict__ Wo, const float* __restrict__ Wg,
    u16* __restrict__ Xb, u16* __restrict__ Wb) {
  int blk = blockIdx.x;
  int col = threadIdx.x * 4;
  const float* src;
  u16* dst;
  if (blk < BATCH) {
    src = (col < HID) ? (prev_h + (size_t)blk * HID + col)
                      : (input_ + (size_t)blk * HID + (col - HID));
    dst = Xb + (size_t)blk * KDIM + col;
  } else {
    int grow = blk - BATCH;               // 0..2047, order [Wi|Wf|Wo|Wg]
    int gate = grow >> 9;
    int n = grow & (HID - 1);
    const float* s = gate == 0 ? Wi : gate == 1 ? Wf : gate == 2 ? Wo : Wg;
    src = s + (size_t)n * KDIM + col;
    dst = Wb + (size_t)grow * KDIM + col;
  }
  float4 v = *(const float4*)src;
  ushort4 o;
  o.x = f2bf(v.x); o.y = f2bf(v.y); o.z = f2bf(v.z); o.w = f2bf(v.w);
  *(ushort4*)dst = o;
}

// ---------- main fused GEMM + LSTM epilogue ----------
// R2 was staging-BW-bound: 1.05 GB logical global->LDS at ~13 B/cyc/CU.
// This version: 256x256-eff tile (8 waves), halves staged bytes to 537 MB,
// plus BK=32 LDS double-buffer (2x32KB) so the 1-block/CU residency still
// overlaps staging with compute (loads for k+1 fly during compute(k); the
// compiler's vmcnt(0)-at-barrier only waits the residual).
//
// XOR swizzle (4 chunks of 16B per 32-elem row): LDS slot (row,p) holds
// global chunk p^(row&3); staging lane l fetches chunk (l&3)^((l>>2)&3);
// fragment reads use chunk c^(lrow&3) -> 4-way bank aliasing at full rate.
__global__ __launch_bounds__(512, 2) void lstm_gemm_kernel(
    const u16* __restrict__ Xb, const u16* __restrict__ Wb,
    const float* __restrict__ Bi, const float* __restrict__ Bf,
    const float* __restrict__ Bo, const float* __restrict__ Bg,
    const float* __restrict__ prevC, float* __restrict__ out) {
  __shared__ u16 lds[2][16384];   // per buf: A=[0,8192) 256x32, B=[8192,16384)

  const int tid = threadIdx.x;
  const int wave = tid >> 6, lane = tid & 63;
  const int lrow = lane & 15, lquad = lane >> 4;
  const int m_block = blockIdx.x * BM;
  const int nb = blockIdx.y * BNG;          // per-gate col base
  const int m_off = (wave >> 1) * 64;       // wave M position (4 waves)
  const int n_off = (wave & 1) * 32;        // wave per-gate N position (2)

  // Staging: per fill 32 KB = 32 wave-instrs, 4 per wave (2 A + 2 B).
  // One instr covers 16 rows x 32 k; lane l -> row +(l>>2), swizzled chunk.
  const int swz = (((lane & 3) ^ ((lane >> 2) & 3)) * 8);
  const u16* gp[4];
  int lp[4];                                 // u16 offset into lds[0]
#pragma unroll
  for (int i = 0; i < 4; ++i) {
    int base = wave * 32 + (i & 1) * 16;     // row-group base, 0..240
    int r = base + (lane >> 2);              // 0..255
    if (i < 2) {
      gp[i] = Xb + (size_t)(m_block + r) * KDIM + swz;
      lp[i] = base * 32;
    } else {
      int gate = r >> 6, col = r & 63;
      gp[i] = Wb + (size_t)(gate * HID + nb + col) * KDIM + swz;
      lp[i] = 8192 + base * 32;
    }
  }

  floatx4 acc[4][2][4];   // [gate][n-tile][m-tile]
#pragma unroll
  for (int g = 0; g < 4; ++g)
#pragma unroll
    for (int nt = 0; nt < 2; ++nt)
#pragma unroll
      for (int mt = 0; mt < 4; ++mt)
        acc[g][nt][mt] = (floatx4){0.f, 0.f, 0.f, 0.f};

  const int roff = ((lquad ^ (lrow & 3)) * 8);   // swizzled element offset

  auto fill = [&](int buf, int k0) {
#pragma unroll
    for (int i = 0; i < 4; ++i)
      async_copy16(gp[i] + k0, &lds[0][0] + buf * 16384 + lp[i]);
  };

  auto compute = [&](int buf) {
    const u16* LA = &lds[buf][0];
    const u16* LB = &lds[buf][8192];
    bf16x8 a[4], b[4][2];
#pragma unroll
    for (int mt = 0; mt < 4; ++mt)
      a[mt] = *(const bf16x8*)&LA[(m_off + mt * 16 + lrow) * 32 + roff];
#pragma unroll
    for (int g = 0; g < 4; ++g)
#pragma unroll
      for (int nt = 0; nt < 2; ++nt)
        b[g][nt] = *(const bf16x8*)
            &LB[(g * 64 + n_off + nt * 16 + lrow) * 32 + roff];
#pragma unroll
    for (int g = 0; g < 4; ++g)
#pragma unroll
      for (int nt = 0; nt < 2; ++nt)
#pragma unroll
        for (int mt = 0; mt < 4; ++mt)
          acc[g][nt][mt] = __builtin_amdgcn_mfma_f32_16x16x32_bf16(
              a[mt], b[g][nt], acc[g][nt][mt], 0, 0, 0);
  };

  fill(0, 0);
  for (int k0 = 0; k0 < KDIM; k0 += 2 * BK) {
    __syncthreads();                 // drains fill(buf0) residual
    fill(1, k0 + BK);                // flies during compute(0)
    compute(0);
    __syncthreads();                 // drains fill(buf1) residual
    if (k0 + 2 * BK < KDIM) fill(0, k0 + 2 * BK);
    compute(1);
  }

  // Epilogue. C layout (verified m89/R1): col=lane&15, row=lquad*4+reg.
  float* outH = out;
  float* outC = out + (size_t)BATCH * HID;
#pragma unroll
  for (int nt = 0; nt < 2; ++nt) {
    const int j = nb + n_off + nt * 16 + lrow;
    const float vbi = Bi[j], vbf = Bf[j], vbo = Bo[j], vbg = Bg[j];
#pragma unroll
    for (int mt = 0; mt < 4; ++mt) {
      int rowb = m_block + m_off + mt * 16 + lquad * 4;
#pragma unroll
      for (int r = 0; r < 4; ++r) {
        int row = rowb + r;
        float gi = fast_sigmoid(acc[0][nt][mt][r] + vbi);
        float gf = fast_sigmoid(acc[1][nt][mt][r] + vbf);
        float go = fast_sigmoid(acc[2][nt][mt][r] + vbo);
        float gg = fast_tanh(acc[3][nt][mt][r] + vbg);
        float c = gf * prevC[row * HID + j] + gi * gg;
        float h = fast_tanh(c) * go;
        outH[row * HID + j] = h;
        outC[row * HID + j] = c;
      }
    }
  }
}

// ---------- slow fallback if ws too small (correctness insurance) ----------
__global__ void lstm_fallback_kernel(
    const float* __restrict__ input_, const float* __restrict__ prev_h,
    const float* __restrict__ prevC,
    const float* __restrict__ Wi, const float* __restrict__ Bi,
    const float* __restrict__ Wf, const float* __restrict__ Bf,
    const float* __restrict__ Wo, const float* __restrict__ Bo,
    const float* __restrict__ Wg, const float* __restrict__ Bg,
    float* __restrict__ out) {
  int idx = blockIdx.x * blockDim.x + threadIdx.x;
  int b = idx / HID, j = idx % HID;
  if (b >= BATCH) return;
  float si = 0.f, sf = 0.f, so = 0.f, sg = 0.f;
  for (int k = 0; k < KDIM; ++k) {
    float x = (k < HID) ? prev_h[b * HID + k] : input_[b * HID + (k - HID)];
    si += x * Wi[j * KDIM + k];
    sf += x * Wf[j * KDIM + k];
    so += x * Wo[j * KDIM + k];
    sg += x * Wg[j * KDIM + k];
  }
  float gi = fast_sigmoid(si + Bi[j]);
  float gf = fast_sigmoid(sf + Bf[j]);
  float go = fast_sigmoid(so + Bo[j]);
  float gg = fast_tanh(sg + Bg[j]);
  float c = gf * prevC[b * HID + j] + gi * gg;
  out[b * HID + j] = fast_tanh(c) * go;
  out[(size_t)BATCH * HID + b * HID + j] = c;
}

extern "C" void kernel_launch(void* const* d_in, const int* in_sizes, int n_in,
                              void* d_out, int out_size, void* d_ws, size_t ws_size,
                              hipStream_t stream) {
  const float* input_ = (const float*)d_in[0];
  const float* prev_h = (const float*)d_in[1];
  const float* prev_c = (const float*)d_in[2];
  const float* W_i = (const float*)d_in[3];
  const float* b_i = (const float*)d_in[4];
  const float* W_f = (const float*)d_in[5];
  const float* b_f = (const float*)d_in[6];
  const float* W_g = (const float*)d_in[7];
  const float* b_g = (const float*)d_in[8];
  const float* W_o = (const float*)d_in[9];
  const float* b_o = (const float*)d_in[10];
  float* out = (float*)d_out;

  const size_t ws_needed =
      (size_t)BATCH * KDIM * sizeof(u16) + (size_t)4 * HID * KDIM * sizeof(u16);

  if (ws_size < ws_needed) {
    int total = BATCH * HID;
    lstm_fallback_kernel<<<(total + 255) / 256, 256, 0, stream>>>(
        input_, prev_h, prev_c, W_i, b_i, W_f, b_f, W_o, b_o, W_g, b_g, out);
    return;
  }

  u16* Xb = (u16*)d_ws;                       // 16384 x 1024 bf16 = 33.5 MB
  u16* Wb = Xb + (size_t)BATCH * KDIM;        // 2048  x 1024 bf16 =  4  MB

  pack_kernel<<<BATCH + 4 * HID, 256, 0, stream>>>(input_, prev_h,
                                                   W_i, W_f, W_o, W_g, Xb, Wb);

  dim3 grid(BATCH / BM, HID / BNG);           // 64 x 8 = 512 blocks
  lstm_gemm_kernel<<<grid, 512, 0, stream>>>(Xb, Wb, b_i, b_f, b_o, b_g,
                                             prev_c, out);
}

// Round 4
// 241.138 us; speedup vs baseline: 1.0308x; 1.0308x over previous
//
#include <hip/hip_runtime.h>
#include <hip/hip_bf16.h>
#include <math.h>

typedef unsigned short u16;

#define BATCH 16384
#define HID   512
#define KDIM  1024   // INPUT + HIDDEN
#define BM    128    // batch rows per block
#define BNG   128    // per-gate cols per block (x4 gates = 512 effective)
#define NSTEP 16     // K-steps of 64

typedef __bf16 bf16x8 __attribute__((ext_vector_type(8)));
typedef float  floatx4 __attribute__((ext_vector_type(4)));

__device__ __forceinline__ void async_copy16(const void* g, void* l) {
  __builtin_amdgcn_global_load_lds(
      (const __attribute__((address_space(1))) void*)g,
      (__attribute__((address_space(3))) void*)l, 16, 0, 0);
}

__device__ __forceinline__ float fast_sigmoid(float x) {
  return 1.0f / (1.0f + __expf(-x));
}
__device__ __forceinline__ float fast_tanh(float x) {
  float e = __expf(-2.0f * fabsf(x));
  float t = (1.0f - e) / (1.0f + e);
  return x >= 0.0f ? t : -t;
}
__device__ __forceinline__ u16 f2bf(float f) {
  return __builtin_bit_cast(u16, __float2bfloat16(f));
}

// ---------- pre-pass: fp32 -> bf16 packing ----------
// Xb: row-major [BATCH][KDIM], X[b] = [prev_h[b] | input_[b]].
// Wf: MFMA-FRAGMENT-MAJOR weights so B-loads are one coalesced dwordx4:
//   elem (gate g, per-gate col n, k) lives at
//   (((g*32 + n/16)*32 + k/32)*64 + ((k>>3)&3)*16 + (n&15))*8 + (k&7)
//   i.e. [tile128][kstep32][lane64][8elems]; lane = lquad*16+lrow gives
//   B[n = tile*16+lrow][k = kstep*32 + lquad*8 .. +8] — the verified
//   B-fragment layout from R1-R3.
__global__ __launch_bounds__(256) void pack_kernel(
    const float* __restrict__ input_, const float* __restrict__ prev_h,
    const float* __restrict__ Wi, const float* __restrict__ Wf_,
    const float* __restrict__ Wo, const float* __restrict__ Wg,
    u16* __restrict__ Xb, u16* __restrict__ Wf) {
  int blk = blockIdx.x;
  int k = threadIdx.x * 4;
  if (blk < BATCH) {
    const float* src = (k < HID) ? (prev_h + (size_t)blk * HID + k)
                                 : (input_ + (size_t)blk * HID + (k - HID));
    float4 v = *(const float4*)src;
    ushort4 o;
    o.x = f2bf(v.x); o.y = f2bf(v.y); o.z = f2bf(v.z); o.w = f2bf(v.w);
    *(ushort4*)(Xb + (size_t)blk * KDIM + k) = o;
  } else {
    int grow = blk - BATCH;               // 0..2047, order [Wi|Wf|Wo|Wg]
    int g = grow >> 9;
    int n = grow & (HID - 1);
    const float* s = g == 0 ? Wi : g == 1 ? Wf_ : g == 2 ? Wo : Wg;
    float4 v = *(const float4*)(s + (size_t)n * KDIM + k);
    ushort4 o;
    o.x = f2bf(v.x); o.y = f2bf(v.y); o.z = f2bf(v.z); o.w = f2bf(v.w);
    size_t d = ((size_t)((g * 32 + (n >> 4)) * 32 + (k >> 5)) * 64 +
                ((k >> 3) & 3) * 16 + (n & 15)) * 8 + (k & 7);
    *(ushort4*)(Wf + d) = o;   // k%8 in {0,4} -> 8B-aligned
  }
}

// ---------- main fused GEMM + LSTM epilogue ----------
// R3 lesson: both tiles through global_load_lds -> every barrier's vmcnt(0)
// drain serializes 32KB staging. Here only X (16KB/step) goes through LDS;
// W comes via coalesced register loads from L2 (fragment-major layout),
// which pipeline ACROSS barriers (vmcnt waits only before use).
// Tile: BM=128 x 512 per-gate-eff cols; 8 waves each own one 16-col n-tile
// (zero B redundancy), all waves cover M=128 (A shared via LDS).
// LDS swizzle = R2's measured-zero-conflict scheme (64-elem rows, XOR-8).
__global__ __launch_bounds__(512, 2) void lstm_gemm_kernel(
    const u16* __restrict__ Xb, const u16* __restrict__ Wf,
    const float* __restrict__ Bi, const float* __restrict__ Bf,
    const float* __restrict__ Bo, const float* __restrict__ Bg,
    const float* __restrict__ prevC, float* __restrict__ out) {
  __shared__ u16 lds[2][8192];   // per buf: 128 rows x 64 elems = 16 KB

  const int tid = threadIdx.x;
  const int wave = tid >> 6, lane = tid & 63;
  const int lrow = lane & 15, lquad = lane >> 4;
  const int m_block = blockIdx.x * BM;
  const int ntg = blockIdx.y * 8 + wave;   // global per-gate 16-col tile id

  // A staging: 16 instrs per 16KB fill, 2 per wave. Instr li covers rows
  // li*8+(lane>>3); lane fetches swizzled 16B chunk (l&7)^(l>>3).
  const int swz = ((lane & 7) ^ ((lane >> 3) & 7)) * 8;
  const u16* gp[2];
  int lp[2];
#pragma unroll
  for (int i = 0; i < 2; ++i) {
    int li = wave * 2 + i;
    gp[i] = Xb + (size_t)(m_block + li * 8 + (lane >> 3)) * KDIM + swz;
    lp[i] = li * 512;
  }

  floatx4 acc[4][8];   // [gate][m-tile]
#pragma unroll
  for (int g = 0; g < 4; ++g)
#pragma unroll
    for (int mt = 0; mt < 8; ++mt)
      acc[g][mt] = (floatx4){0.f, 0.f, 0.f, 0.f};

  auto fill = [&](int buf, int S) {
#pragma unroll
    for (int i = 0; i < 2; ++i)
      async_copy16(gp[i] + S * 64, &lds[0][0] + buf * 8192 + lp[i]);
  };

  // B register loads: one coalesced dwordx4 per (kk,gate); pipeline across
  // barriers since they have no LDS-ordering dependency.
  auto loadB = [&](int S, bf16x8 (&dst)[2][4]) {
#pragma unroll
    for (int kk = 0; kk < 2; ++kk)
#pragma unroll
      for (int g = 0; g < 4; ++g)
        dst[kk][g] = *(const bf16x8*)(
            Wf + (((size_t)(g * 32 + ntg) * 32 + (S * 2 + kk)) << 9) +
            lane * 8);
  };

  auto compute = [&](int buf, bf16x8 (&B)[2][4]) {
    const u16* LA = &lds[buf][0];
#pragma unroll
    for (int kk = 0; kk < 2; ++kk) {
#pragma unroll
      for (int mt = 0; mt < 8; ++mt) {
        bf16x8 a = *(const bf16x8*)
            &LA[(mt * 16 + lrow) * 64 + (((kk * 4 + lquad) ^ (lrow & 7)) * 8)];
#pragma unroll
        for (int g = 0; g < 4; ++g)
          acc[g][mt] = __builtin_amdgcn_mfma_f32_16x16x32_bf16(
              a, B[kk][g], acc[g][mt], 0, 0, 0);
      }
    }
  };

  bf16x8 b0[2][4], b1[2][4];
  loadB(0, b0);
  fill(0, 0);
  for (int S = 0; S < NSTEP; S += 2) {
    __syncthreads();                    // drains fill(buf0) (had full window)
    fill(1, S + 1);                     // S+1 <= 15 always
    loadB(S + 1 < NSTEP ? S + 1 : S, b1);
    compute(0, b0);
    __syncthreads();                    // drains fill(buf1)
    if (S + 2 < NSTEP) {
      fill(0, S + 2);
      loadB(S + 2, b0);
    }
    compute(1, b1);
  }

  // Epilogue. C layout (verified): col=lane&15, row=lquad*4+reg.
  const int j = ntg * 16 + lrow;        // 0..511
  const float vbi = Bi[j], vbf = Bf[j], vbo = Bo[j], vbg = Bg[j];
  float* outH = out;
  float* outC = out + (size_t)BATCH * HID;
#pragma unroll
  for (int mt = 0; mt < 8; ++mt) {
    int rowb = m_block + mt * 16 + lquad * 4;
#pragma unroll
    for (int r = 0; r < 4; ++r) {
      int row = rowb + r;
      float gi = fast_sigmoid(acc[0][mt][r] + vbi);
      float gf = fast_sigmoid(acc[1][mt][r] + vbf);
      float go = fast_sigmoid(acc[2][mt][r] + vbo);
      float gg = fast_tanh(acc[3][mt][r] + vbg);
      float c = gf * prevC[row * HID + j] + gi * gg;
      float h = fast_tanh(c) * go;
      outH[row * HID + j] = h;
      outC[row * HID + j] = c;
    }
  }
}

// ---------- slow fallback if ws too small (correctness insurance) ----------
__global__ void lstm_fallback_kernel(
    const float* __restrict__ input_, const float* __restrict__ prev_h,
    const float* __restrict__ prevC,
    const float* __restrict__ Wi, const float* __restrict__ Bi,
    const float* __restrict__ Wf, const float* __restrict__ Bf,
    const float* __restrict__ Wo, const float* __restrict__ Bo,
    const float* __restrict__ Wg, const float* __restrict__ Bg,
    float* __restrict__ out) {
  int idx = blockIdx.x * blockDim.x + threadIdx.x;
  int b = idx / HID, j = idx % HID;
  if (b >= BATCH) return;
  float si = 0.f, sf = 0.f, so = 0.f, sg = 0.f;
  for (int k = 0; k < KDIM; ++k) {
    float x = (k < HID) ? prev_h[b * HID + k] : input_[b * HID + (k - HID)];
    si += x * Wi[j * KDIM + k];
    sf += x * Wf[j * KDIM + k];
    so += x * Wo[j * KDIM + k];
    sg += x * Wg[j * KDIM + k];
  }
  float gi = fast_sigmoid(si + Bi[j]);
  float gf = fast_sigmoid(sf + Bf[j]);
  float go = fast_sigmoid(so + Bo[j]);
  float gg = fast_tanh(sg + Bg[j]);
  float c = gf * prevC[b * HID + j] + gi * gg;
  out[b * HID + j] = fast_tanh(c) * go;
  out[(size_t)BATCH * HID + b * HID + j] = c;
}

extern "C" void kernel_launch(void* const* d_in, const int* in_sizes, int n_in,
                              void* d_out, int out_size, void* d_ws, size_t ws_size,
                              hipStream_t stream) {
  const float* input_ = (const float*)d_in[0];
  const float* prev_h = (const float*)d_in[1];
  const float* prev_c = (const float*)d_in[2];
  const float* W_i = (const float*)d_in[3];
  const float* b_i = (const float*)d_in[4];
  const float* W_f = (const float*)d_in[5];
  const float* b_f = (const float*)d_in[6];
  const float* W_g = (const float*)d_in[7];
  const float* b_g = (const float*)d_in[8];
  const float* W_o = (const float*)d_in[9];
  const float* b_o = (const float*)d_in[10];
  float* out = (float*)d_out;

  const size_t ws_needed =
      (size_t)BATCH * KDIM * sizeof(u16) + (size_t)4 * HID * KDIM * sizeof(u16);

  if (ws_size < ws_needed) {
    int total = BATCH * HID;
    lstm_fallback_kernel<<<(total + 255) / 256, 256, 0, stream>>>(
        input_, prev_h, prev_c, W_i, b_i, W_f, b_f, W_o, b_o, W_g, b_g, out);
    return;
  }

  u16* Xb = (u16*)d_ws;                       // 16384 x 1024 bf16 = 33.5 MB
  u16* Wf = Xb + (size_t)BATCH * KDIM;        // fragment-major, 4 MB

  pack_kernel<<<BATCH + 4 * HID, 256, 0, stream>>>(input_, prev_h,
                                                   W_i, W_f, W_o, W_g, Xb, Wf);

  dim3 grid(BATCH / BM, HID / BNG);           // 128 x 4 = 512 blocks
  lstm_gemm_kernel<<<grid, 512, 0, stream>>>(Xb, Wf, b_i, b_f, b_o, b_g,
                                             prev_c, out);
}